// Round 8
// baseline (175.394 us; speedup 1.0000x reference)
//
#include <hip/hip_runtime.h>

// RoiPooling: crop + bilinear 7x7 resize, TF1 resize_bilinear (align_corners=False).
// feat: (128,128,1024) fp32, rois: (512,4) fp32 [ymin,xmin,ymax,xmax], out: (512,7,7,1024) fp32.
//
// R10: chunked sorted-ROI -> XCD assignment.
// Model from R2..R9 nulls: read side is L2-miss-occupancy (MSHR) limited at
// ~2 TB/s (time == FETCH / 2TB/s: 122MB/62us checks exactly); writes are free
// (fillBuffer 6.5 TB/s). Only lever: reduce unique L2-miss bytes.
// R7's sort was STRIDED across XCDs (rslot = 8q + k%8): adjacent sorted ROIs
// (max overlap) landed on DIFFERENT XCDs -> shared lines fetched into up to 8
// L2s; each XCD got a stride-8 comb (consec. ROIs ~16 ymin rows apart, ~no
// overlap). Fix: XCD j gets the CONTIGUOUS sorted run [64j, 64j+64): adjacent
// ROIs on one XCD differ by ~0.25 ymin rows -> ~95% y-overlap; each map line
// fetched by ~1 XCD. Expect FETCH 122 -> 70-90MB, dispatch 62 -> ~38-52us.
// Body = R4 (best measured): 128 thr x 2 float4, dead-tap skip (bit-exact),
// nt stores.

#define POOL_P 7
#define FEAT_C 1024
#define FEAT_W 128
#define CELLS_PER_ROI (POOL_P * POOL_P)          // 49
#define N_ROIS 512
#define ROIS_PER_XCD (N_ROIS / 8)                // 64

typedef float vfloat4 __attribute__((ext_vector_type(4)));

// ---- 1-block bitonic sort: key = ((ymin<<7)|xmin)<<10 | idx --------------
__global__ __launch_bounds__(N_ROIS) void roi_sort_kernel(
    const float* __restrict__ rois, unsigned* __restrict__ perm)
{
    __shared__ unsigned sk[N_ROIS];
    const int tid = threadIdx.x;
    {
        const vfloat4 roi = ((const vfloat4*)rois)[tid];
        const unsigned ymin = (unsigned)(int)roi.x;   // [0,126]
        const unsigned xmin = (unsigned)(int)roi.y;   // [0,126]
        sk[tid] = (((ymin << 7) | xmin) << 10) | (unsigned)tid;
    }
    __syncthreads();
    for (int k = 2; k <= N_ROIS; k <<= 1) {
        for (int j = k >> 1; j > 0; j >>= 1) {
            const int ixj = tid ^ j;
            if (ixj > tid) {
                const bool up = ((tid & k) == 0);
                const unsigned a = sk[tid], b = sk[ixj];
                if ((a > b) == up) { sk[tid] = b; sk[ixj] = a; }
            }
            __syncthreads();
        }
    }
    perm[tid] = sk[tid] & 1023u;
}

// ---- main kernel: R4 body + chunked slot mapping -------------------------
__global__ __launch_bounds__(128) void roi_pool_kernel(
    const float* __restrict__ feat,
    const float* __restrict__ rois,
    float* __restrict__ out,
    const unsigned* __restrict__ perm)
{
    // CHUNKED mapping: blockIdx%8 (heuristic XCD id) selects a contiguous run
    // of 64 sorted ROIs; within the run, blocks walk cell-fastest then ROI.
    const int i     = blockIdx.x;
    const int xcd   = i & 7;
    const int n     = i >> 3;                    // [0, 3136) = 64 ROIs x 49 cells
    const int sIdx  = n / CELLS_PER_ROI;         // [0,64) slot within chunk
    const int cell  = n - sIdx * CELLS_PER_ROI;  // [0,49)
    const int rslot = xcd * ROIS_PER_XCD + sIdx; // sorted-order slot
    const int px    = cell % POOL_P;
    const int py    = cell / POOL_P;

    // Map slot -> real ROI id via spatial sort (uniform scalar load).
    const int r = perm ? (int)perm[rslot] : rslot;

    // ---- ROI box (block-uniform scalar math)
    const vfloat4 roi = ((const vfloat4*)rois)[r];
    const int ymin = (int)roi.x;
    const int xmin = (int)roi.y;
    const int ymax = (int)roi.z;
    const int xmax = (int)roi.w;

    const float h = (float)(ymax - ymin + 1);
    const float w = (float)(xmax - xmin + 1);

    // NB: exact reference rounding: src = py * (h / 7.0f)
    const float src_y = (float)py * (h / 7.0f);
    const float src_x = (float)px * (w / 7.0f);

    const int y0 = (int)floorf(src_y);
    const int x0 = (int)floorf(src_x);
    const int y1 = min(y0 + 1, ymax - ymin);
    const int x1 = min(x0 + 1, xmax - xmin);

    const float fy = src_y - (float)y0;
    const float fx = src_x - (float)x0;

    // Dead-tap analysis (uniform across the block) — bit-exact substitutions:
    //  !nx: fx==0 (tr weight exactly 0) or x1==x0 (tr IS tl) -> skip tr.
    //  !ny: fy==0 or y1==y0 -> skip bl. br needs both.
    const bool nx = (x1 != x0) && (fx != 0.0f);
    const bool ny = (y1 != y0) && (fy != 0.0f);

    const int gy0 = ymin + y0;
    const int gy1 = ymin + y1;
    const int gx0 = xmin + x0;
    const int gx1 = xmin + x1;

    const vfloat4* __restrict__ tlp = (const vfloat4*)(feat + ((size_t)(gy0 * FEAT_W + gx0)) * FEAT_C);
    const vfloat4* __restrict__ trp = (const vfloat4*)(feat + ((size_t)(gy0 * FEAT_W + gx1)) * FEAT_C);
    const vfloat4* __restrict__ blp = (const vfloat4*)(feat + ((size_t)(gy1 * FEAT_W + gx0)) * FEAT_C);
    const vfloat4* __restrict__ brp = (const vfloat4*)(feat + ((size_t)(gy1 * FEAT_W + gx1)) * FEAT_C);
    vfloat4* __restrict__ op = (vfloat4*)(out + ((size_t)r * CELLS_PER_ROI + cell) * FEAT_C);

    const int t0 = threadIdx.x;                  // [0,128)
    const int t1 = t0 + 128;

    // Issue all live loads before any use (max outstanding vmcnt).
    const vfloat4 tl0 = tlp[t0];
    const vfloat4 tl1 = tlp[t1];
    vfloat4 tr0, tr1, bl0, bl1, br0, br1;
    if (nx)       { tr0 = trp[t0]; tr1 = trp[t1]; }
    if (ny)       { bl0 = blp[t0]; bl1 = blp[t1]; }
    if (nx && ny) { br0 = brp[t0]; br1 = brp[t1]; }

    // Exact fallbacks for skipped taps.
    if (!nx) { tr0 = tl0; tr1 = tl1; }
    if (!ny) { bl0 = tl0; bl1 = tl1; }
    if (!(nx && ny)) {
        br0 = (!nx) ? bl0 : tr0;    // !nx: br:=bl (bot=bl exactly); !ny: br:=tr (bot=top)
        br1 = (!nx) ? bl1 : tr1;
    }

    vfloat4 res0, res1;
    {
        float top, bot;
        top = tl0.x + (tr0.x - tl0.x) * fx; bot = bl0.x + (br0.x - bl0.x) * fx; res0.x = top + (bot - top) * fy;
        top = tl0.y + (tr0.y - tl0.y) * fx; bot = bl0.y + (br0.y - bl0.y) * fx; res0.y = top + (bot - top) * fy;
        top = tl0.z + (tr0.z - tl0.z) * fx; bot = bl0.z + (br0.z - bl0.z) * fx; res0.z = top + (bot - top) * fy;
        top = tl0.w + (tr0.w - tl0.w) * fx; bot = bl0.w + (br0.w - bl0.w) * fx; res0.w = top + (bot - top) * fy;
        top = tl1.x + (tr1.x - tl1.x) * fx; bot = bl1.x + (br1.x - bl1.x) * fx; res1.x = top + (bot - top) * fy;
        top = tl1.y + (tr1.y - tl1.y) * fx; bot = bl1.y + (br1.y - bl1.y) * fx; res1.y = top + (bot - top) * fy;
        top = tl1.z + (tr1.z - tl1.z) * fx; bot = bl1.z + (br1.z - bl1.z) * fx; res1.z = top + (bot - top) * fy;
        top = tl1.w + (tr1.w - tl1.w) * fx; bot = bl1.w + (br1.w - bl1.w) * fx; res1.w = top + (bot - top) * fy;
    }

    // Write-once output: keep it out of the caches.
    __builtin_nontemporal_store(res0, &op[t0]);
    __builtin_nontemporal_store(res1, &op[t1]);
}

extern "C" void kernel_launch(void* const* d_in, const int* in_sizes, int n_in,
                              void* d_out, int out_size, void* d_ws, size_t ws_size,
                              hipStream_t stream) {
    const float* feat = (const float*)d_in[0];   // (1,128,128,1024) fp32
    const float* rois = (const float*)d_in[1];   // (512,4) fp32
    float* out        = (float*)d_out;           // (512, 7*7*1024) fp32

    const int n_rois   = in_sizes[1] / 4;              // 512
    const int n_blocks = n_rois * CELLS_PER_ROI;       // 25088

    unsigned* perm = nullptr;
    if (n_rois == N_ROIS && ws_size >= N_ROIS * sizeof(unsigned)) {
        perm = (unsigned*)d_ws;
        roi_sort_kernel<<<1, N_ROIS, 0, stream>>>(rois, perm);
    }
    roi_pool_kernel<<<n_blocks, 128, 0, stream>>>(feat, rois, out, perm);
}